// Round 3
// baseline (113.541 us; speedup 1.0000x reference)
//
#include <hip/hip_runtime.h>
#include <hip/hip_bf16.h>
#include <math.h>

// Problem dims (fixed by reference)
constexpr int Bn = 8, Sn = 1024, Fn = 32, Dn = 128, Cc = 16;
constexpr int NSITE = Bn * Sn;
constexpr int SPB = 4;                 // sites per block (pipelined)

#define EPSV 1e-8f

typedef __attribute__((ext_vector_type(8))) short bf16x8;
typedef __attribute__((ext_vector_type(4))) short bf16x4;
typedef __attribute__((ext_vector_type(4))) float f32x4;

__device__ inline short f2bf(float x) {
    __hip_bfloat16 h = __float2bfloat16(x);   // RNE
    short s;
    __builtin_memcpy(&s, &h, sizeof(s));
    return s;
}

__device__ inline bf16x8 cvt8(float4 x0, float4 x1) {
    bf16x8 r;
    r[0] = f2bf(x0.x); r[1] = f2bf(x0.y); r[2] = f2bf(x0.z); r[3] = f2bf(x0.w);
    r[4] = f2bf(x1.x); r[5] = f2bf(x1.y); r[6] = f2bf(x1.z); r[7] = f2bf(x1.w);
    return r;
}

// ---------------------------------------------------------------------------
// Kernel 1: normalize Cj [16,128] and pack into MFMA B-fragment bf16 layout.
// B[k][c]: kt=k>>5, lane=((k>>3)&3)*16+c, j=k&7 -> CnPack[(kt*64+lane)*8+j]
// ---------------------------------------------------------------------------
__global__ void normC_kernel(const float* __restrict__ Cj, short* __restrict__ CnPack) {
    int c = blockIdx.x;       // 16 blocks
    int d = threadIdx.x;      // 128 threads (k index)
    float v = Cj[c * Dn + d];
    float sq = v * v;
    #pragma unroll
    for (int off = 32; off > 0; off >>= 1) sq += __shfl_down(sq, off);
    __shared__ float part[2];
    if ((d & 63) == 0) part[d >> 6] = sq;
    __syncthreads();
    float nrm = sqrtf(part[0] + part[1]);
    float cn = v / fmaxf(nrm, EPSV);
    int kt = d >> 5, ln = ((d >> 3) & 3) * 16 + c, j = d & 7;
    CnPack[(kt * 64 + ln) * 8 + j] = f2bf(cn);
}

// ---------------------------------------------------------------------------
// Kernel 2: pack W [128(out),128(in)] fp32 -> bf16 MFMA B-fragment layout.
// ---------------------------------------------------------------------------
__global__ void packW_kernel(const float* __restrict__ W, short* __restrict__ Wb) {
    int t = blockIdx.x * 256 + threadIdx.x;   // 16384
    int n = t >> 7, k = t & 127;
    short v = f2bf(W[n * Dn + k]);
    int frag = (n >> 4) * 4 + (k >> 5);
    int lane = ((k >> 3) & 3) * 16 + (n & 15);
    int j = k & 7;
    Wb[(frag * 64 + lane) * 8 + j] = v;
}

// ---------------------------------------------------------------------------
// Kernel 3: SPB sites per block, 256 threads = 4 waves, reg-staged prefetch.
// ---------------------------------------------------------------------------
__launch_bounds__(256, 4)
__global__ void site_kernel(const float* __restrict__ Hs,
                            const short* __restrict__ CnPack,
                            const short* __restrict__ Wb,
                            const float* __restrict__ bvec,
                            const float* __restrict__ imp_in,
                            float* __restrict__ f_out,
                            float* __restrict__ imp_out) {
    // sHb: rows 256B, 16B chunks XOR-swizzled by (row&7) -> 2-way max (free)
    __shared__ __align__(16) short sHb[32][128];
    // F_tjT: [dim n][feature f], 80B rows (16-aligned), 2-way max
    __shared__ __align__(16) short F_tjT[128][40];
    // sWgT: [center c][feature f] fp32, 144B rows (16-aligned)
    __shared__ __align__(16) float sWgT[16][36];
    __shared__ float sInv[32];

    const int tid  = threadIdx.x;
    const int w    = tid >> 6;       // wave 0..3
    const int lane = tid & 63;
    const int c16  = lane & 15;
    const int g    = lane >> 4;

    const int site0 = blockIdx.x * SPB;

    // hoisted invariants
    const float bias0 = bvec[32 * w + c16];
    const float bias1 = bvec[32 * w + 16 + c16];
    bf16x8 bcf[4];
    if (w == 0) {
        #pragma unroll
        for (int kt = 0; kt < 4; ++kt)
            bcf[kt] = *(const bf16x8*)&CnPack[(kt * 64 + lane) * 8];
    }

    // staging map: thread -> (row r, 16-float seg q); coalesced 64B/thread
    const int r = tid >> 3, q = tid & 7;
    const float4* hp = (const float4*)(Hs + (size_t)site0 * (Fn * Dn)) + r * 32 + q * 4;

    // prologue: load site0
    float4 x0 = hp[0], x1 = hp[1], x2 = hp[2], x3 = hp[3];

    const f32x4 zro = {0.f, 0.f, 0.f, 0.f};

    for (int i = 0; i < SPB; ++i) {
        const int site = site0 + i;

        // ---- issue prefetch of next site (latency hides under this site) ----
        float4 y0, y1, y2, y3;
        if (i + 1 < SPB) {
            const float4* np = hp + (size_t)(i + 1) * 1024;
            y0 = np[0]; y1 = np[1]; y2 = np[2]; y3 = np[3];
        }

        // ---- stage current site: fp32 norms + bf16 LDS (swizzled) ----
        {
            float sq = x0.x*x0.x + x0.y*x0.y + x0.z*x0.z + x0.w*x0.w
                     + x1.x*x1.x + x1.y*x1.y + x1.z*x1.z + x1.w*x1.w
                     + x2.x*x2.x + x2.y*x2.y + x2.z*x2.z + x2.w*x2.w
                     + x3.x*x3.x + x3.y*x3.y + x3.z*x3.z + x3.w*x3.w;
            sq += __shfl_xor(sq, 1);
            sq += __shfl_xor(sq, 2);
            sq += __shfl_xor(sq, 4);
            if (q == 0) sInv[r] = 1.0f / fmaxf(sqrtf(sq), EPSV);
            const int sw = r & 7;
            *(bf16x8*)&sHb[r][((2 * q)     ^ sw) * 8] = cvt8(x0, x1);
            *(bf16x8*)&sHb[r][((2 * q + 1) ^ sw) * 8] = cvt8(x2, x3);
        }
        __syncthreads();   // A: sHb, sInv ready

        // ---- Phase 1: Linear MFMA (all waves) + cosine MFMA (wave 0) ----
        f32x4 acc00 = zro, acc01 = zro, acc10 = zro, acc11 = zro;
        f32x4 cos0 = zro, cos1 = zro;
        const int xsw = c16 & 7;
        #pragma unroll
        for (int kt = 0; kt < 4; ++kt) {
            bf16x8 a0 = *(const bf16x8*)&sHb[c16][((kt * 4 + g) ^ xsw) * 8];
            bf16x8 a1 = *(const bf16x8*)&sHb[16 + c16][((kt * 4 + g) ^ xsw) * 8];
            bf16x8 b0 = *(const bf16x8*)&Wb[((w * 8) + kt) * 512 + lane * 8];
            bf16x8 b1 = *(const bf16x8*)&Wb[((w * 8) + 4 + kt) * 512 + lane * 8];
            acc00 = __builtin_amdgcn_mfma_f32_16x16x32_bf16(a0, b0, acc00, 0, 0, 0);
            acc01 = __builtin_amdgcn_mfma_f32_16x16x32_bf16(a0, b1, acc01, 0, 0, 0);
            acc10 = __builtin_amdgcn_mfma_f32_16x16x32_bf16(a1, b0, acc10, 0, 0, 0);
            acc11 = __builtin_amdgcn_mfma_f32_16x16x32_bf16(a1, b1, acc11, 0, 0, 0);
            if (w == 0) {
                cos0 = __builtin_amdgcn_mfma_f32_16x16x32_bf16(a0, bcf[kt], cos0, 0, 0, 0);
                cos1 = __builtin_amdgcn_mfma_f32_16x16x32_bf16(a1, bcf[kt], cos1, 0, 0, 0);
            }
        }

        // ---- Phase 2 (wave 0): softmaxes in-register + importance ----
        if (w == 0) {
            float s0[4], s1[4];
            #pragma unroll
            for (int rr = 0; rr < 4; ++rr) {
                s0[rr] = 5.0f * cos0[rr] * sInv[4 * g + rr];
                s1[rr] = 5.0f * cos1[rr] * sInv[16 + 4 * g + rr];
            }
            // w: softmax over features (in-lane 8 + xor16/xor32 over g)
            float m = s0[0];
            #pragma unroll
            for (int rr = 0; rr < 4; ++rr) { m = fmaxf(m, s0[rr]); m = fmaxf(m, s1[rr]); }
            m = fmaxf(m, __shfl_xor(m, 16));
            m = fmaxf(m, __shfl_xor(m, 32));
            float e0[4], e1[4], sum = 0.f;
            #pragma unroll
            for (int rr = 0; rr < 4; ++rr) {
                e0[rr] = __expf(s0[rr] - m); e1[rr] = __expf(s1[rr] - m);
                sum += e0[rr] + e1[rr];
            }
            sum += __shfl_xor(sum, 16);
            sum += __shfl_xor(sum, 32);
            float inv = 1.0f / sum;
            #pragma unroll
            for (int rr = 0; rr < 4; ++rr) {
                sWgT[c16][4 * g + rr]      = e0[rr] * inv;
                sWgT[c16][16 + 4 * g + rr] = e1[rr] * inv;
            }
            // w3 softmax over centers fused with importance contraction
            const float* impp = imp_in + (size_t)site * Fn;
            float t = 0.f;
            #pragma unroll
            for (int h = 0; h < 2; ++h) {
                #pragma unroll
                for (int rr = 0; rr < 4; ++rr) {
                    float sv = h ? s1[rr] : s0[rr];
                    float m3 = sv;
                    m3 = fmaxf(m3, __shfl_xor(m3, 1));
                    m3 = fmaxf(m3, __shfl_xor(m3, 2));
                    m3 = fmaxf(m3, __shfl_xor(m3, 4));
                    m3 = fmaxf(m3, __shfl_xor(m3, 8));
                    float e3 = __expf(sv - m3);
                    float q3 = e3;
                    q3 += __shfl_xor(q3, 1);
                    q3 += __shfl_xor(q3, 2);
                    q3 += __shfl_xor(q3, 4);
                    q3 += __shfl_xor(q3, 8);
                    t += (e3 / q3) * impp[h * 16 + 4 * g + rr];
                }
            }
            t += __shfl_xor(t, 16);
            t += __shfl_xor(t, 32);
            float mi = t;
            mi = fmaxf(mi, __shfl_xor(mi, 1));
            mi = fmaxf(mi, __shfl_xor(mi, 2));
            mi = fmaxf(mi, __shfl_xor(mi, 4));
            mi = fmaxf(mi, __shfl_xor(mi, 8));
            float ei = __expf(t - mi);
            float si = ei;
            si += __shfl_xor(si, 1);
            si += __shfl_xor(si, 2);
            si += __shfl_xor(si, 4);
            si += __shfl_xor(si, 8);
            if (g == 0) imp_out[(size_t)site * Cc + c16] = ei / si;
        }

        // ---- Phase 3: bias + relu -> F_tjT (bf16, transposed) ----
        {
            #pragma unroll
            for (int mt = 0; mt < 2; ++mt) {
                #pragma unroll
                for (int nt = 0; nt < 2; ++nt) {
                    f32x4 v = (mt == 0) ? (nt == 0 ? acc00 : acc01)
                                        : (nt == 0 ? acc10 : acc11);
                    float bb = nt ? bias1 : bias0;
                    bf16x4 pk;
                    #pragma unroll
                    for (int rr = 0; rr < 4; ++rr) pk[rr] = f2bf(fmaxf(v[rr] + bb, 0.f));
                    int row = 32 * w + 16 * nt + c16;      // output dim n
                    *(bf16x4*)&F_tjT[row][16 * mt + 4 * g] = pk;
                }
            }
        }
        __syncthreads();   // B: F_tjT + sWgT ready

        // ---- Phase 4: f_t_new[c][n] = sum_f w[f][c] * F_tj[f][n] ----
        {
            float4 wv0 = *(const float4*)&sWgT[c16][8 * g];
            float4 wv1 = *(const float4*)&sWgT[c16][8 * g + 4];
            bf16x8 wA = cvt8(wv0, wv1);
            float* op = f_out + (size_t)site * (Cc * Dn);
            #pragma unroll
            for (int nt = 0; nt < 2; ++nt) {
                int n = 32 * w + 16 * nt + c16;
                bf16x8 bF = *(const bf16x8*)&F_tjT[n][8 * g];
                f32x4 r4 = __builtin_amdgcn_mfma_f32_16x16x32_bf16(wA, bF, zro, 0, 0, 0);
                #pragma unroll
                for (int jj = 0; jj < 4; ++jj)
                    op[(4 * g + jj) * Dn + n] = r4[jj];
            }
        }
        __syncthreads();   // C: all LDS reads done before next-iter overwrite

        if (i + 1 < SPB) { x0 = y0; x1 = y1; x2 = y2; x3 = y3; }
    }
}

// ---------------------------------------------------------------------------
extern "C" void kernel_launch(void* const* d_in, const int* in_sizes, int n_in,
                              void* d_out, int out_size, void* d_ws, size_t ws_size,
                              hipStream_t stream) {
    const float* Hs  = (const float*)d_in[0];
    const float* Cj  = (const float*)d_in[1];
    const float* W   = (const float*)d_in[2];
    const float* b   = (const float*)d_in[3];
    const float* imp = (const float*)d_in[4];

    float* f_out   = (float*)d_out;                          // [B,S,C,D]
    float* imp_out = f_out + (size_t)NSITE * Cc * Dn;        // [B,S,C]

    short* CnPack = (short*)d_ws;                            // 4 KB bf16 frags
    short* Wb     = CnPack + Cc * Dn;                        // 32 KB bf16 frags

    hipLaunchKernelGGL(normC_kernel, dim3(Cc), dim3(Dn), 0, stream, Cj, CnPack);
    hipLaunchKernelGGL(packW_kernel, dim3((Dn * Dn) / 256), dim3(256), 0, stream, W, Wb);
    hipLaunchKernelGGL(site_kernel, dim3(NSITE / SPB), dim3(256), 0, stream,
                       Hs, CnPack, Wb, b, imp, f_out, imp_out);
}

// Round 4
// 51.082 us; speedup vs baseline: 2.2227x; 2.2227x over previous
//
#include <hip/hip_runtime.h>
#include <hip/hip_bf16.h>
#include <math.h>

// Problem dims (fixed by reference)
constexpr int Bn = 8, Sn = 1024, Fn = 32, Dn = 128, Cc = 16;
constexpr int NSITE = Bn * Sn;

#define EPSV 1e-8f

typedef __attribute__((ext_vector_type(8))) short bf16x8;
typedef __attribute__((ext_vector_type(4))) short bf16x4;
typedef __attribute__((ext_vector_type(4))) float f32x4;

__device__ inline short f2bf(float x) {
    __hip_bfloat16 h = __float2bfloat16(x);   // RNE
    short s;
    __builtin_memcpy(&s, &h, sizeof(s));
    return s;
}

__device__ inline bf16x8 cvt8(float4 x0, float4 x1) {
    bf16x8 r;
    r[0] = f2bf(x0.x); r[1] = f2bf(x0.y); r[2] = f2bf(x0.z); r[3] = f2bf(x0.w);
    r[4] = f2bf(x1.x); r[5] = f2bf(x1.y); r[6] = f2bf(x1.z); r[7] = f2bf(x1.w);
    return r;
}

__device__ inline float dot4(float4 v) {
    return v.x * v.x + v.y * v.y + v.z * v.z + v.w * v.w;
}

// ---------------------------------------------------------------------------
// Kernel 1: normalize Cj [16,128] and pack into MFMA B-fragment bf16 layout.
// B[k][c]: kt=k>>5, lane=((k>>3)&3)*16+c, j=k&7 -> CnPack[(kt*64+lane)*8+j]
// ---------------------------------------------------------------------------
__global__ void normC_kernel(const float* __restrict__ Cj, short* __restrict__ CnPack) {
    int c = blockIdx.x;       // 16 blocks
    int d = threadIdx.x;      // 128 threads (k index)
    float v = Cj[c * Dn + d];
    float sq = v * v;
    #pragma unroll
    for (int off = 32; off > 0; off >>= 1) sq += __shfl_down(sq, off);
    __shared__ float part[2];
    if ((d & 63) == 0) part[d >> 6] = sq;
    __syncthreads();
    float nrm = sqrtf(part[0] + part[1]);
    float cn = v / fmaxf(nrm, EPSV);
    int kt = d >> 5, ln = ((d >> 3) & 3) * 16 + c, j = d & 7;
    CnPack[(kt * 64 + ln) * 8 + j] = f2bf(cn);
}

// ---------------------------------------------------------------------------
// Kernel 2: pack W [128(out),128(in)] fp32 -> bf16 MFMA B-fragment layout.
// frag = (n>>4)*4 + (k>>5); lane = ((k>>3)&3)*16 + (n&15); j = k&7
// ---------------------------------------------------------------------------
__global__ void packW_kernel(const float* __restrict__ W, short* __restrict__ Wb) {
    int t = blockIdx.x * 256 + threadIdx.x;   // 16384
    int n = t >> 7, k = t & 127;
    short v = f2bf(W[n * Dn + k]);
    int frag = (n >> 4) * 4 + (k >> 5);
    int lane = ((k >> 3) & 3) * 16 + (n & 15);
    int j = k & 7;
    Wb[(frag * 64 + lane) * 8 + j] = v;
}

// ---------------------------------------------------------------------------
// Kernel 3: ONE WAVE = ONE SITE. 8192 blocks x 64 threads. No barriers.
// ---------------------------------------------------------------------------
__launch_bounds__(64, 4)
__global__ void site_kernel(const float* __restrict__ Hs,
                            const short* __restrict__ CnPack,
                            const short* __restrict__ Wb,
                            const float* __restrict__ bvec,
                            const float* __restrict__ imp_in,
                            float* __restrict__ f_out,
                            float* __restrict__ imp_out) {
    // Per-wave private LDS. 80B rows (16B-aligned for b128, bases 20*r mod 32
    // pairwise <=2-way) -> conflict-free-ish.
    __shared__ __align__(16) short F_tjT[128][40];  // [dim n][feature f] bf16
    __shared__ __align__(16) short sWgT[16][40];    // [center c][feature f] bf16

    const int lane = threadIdx.x;      // 0..63
    const int c16  = lane & 15;
    const int g    = lane >> 4;
    const int site = blockIdx.x;

    const float* hsrc = Hs + (size_t)site * (Fn * Dn);
    const f32x4 zro = {0.f, 0.f, 0.f, 0.f};

    // ---- cos B fragments (normalized centers, packed) ----
    bf16x8 bcf[4];
    #pragma unroll
    for (int kt = 0; kt < 4; ++kt)
        bcf[kt] = *(const bf16x8*)&CnPack[(kt * 64 + lane) * 8];

    // ---- importance inputs for this lane's f-rows ----
    float impv[2][4];
    #pragma unroll
    for (int mt = 0; mt < 2; ++mt)
        #pragma unroll
        for (int r = 0; r < 4; ++r)
            impv[mt][r] = imp_in[(size_t)site * Fn + 16 * mt + 4 * g + r];

    // ---- load Hs -> bf16 A-fragments + fp32 row sum-squares ----
    // A-layout (16x16x32): lane(c16,g) holds A[row=c16][k=8g..8g+7] per kt.
    bf16x8 aF[2][4];
    float sq0 = 0.f, sq1 = 0.f;
    #pragma unroll
    for (int kt = 0; kt < 4; ++kt) {
        const float* p0 = hsrc + c16 * Dn + kt * 32 + g * 8;
        const float* p1 = hsrc + (16 + c16) * Dn + kt * 32 + g * 8;
        float4 a0 = *(const float4*)p0, a1 = *(const float4*)(p0 + 4);
        float4 b0 = *(const float4*)p1, b1 = *(const float4*)(p1 + 4);
        sq0 += dot4(a0) + dot4(a1);
        sq1 += dot4(b0) + dot4(b1);
        aF[0][kt] = cvt8(a0, a1);
        aF[1][kt] = cvt8(b0, b1);
    }
    // reduce over g (lanes with same c16): row norms for rows c16 and 16+c16
    sq0 += __shfl_xor(sq0, 16); sq0 += __shfl_xor(sq0, 32);
    sq1 += __shfl_xor(sq1, 16); sq1 += __shfl_xor(sq1, 32);
    float inv0 = 1.0f / fmaxf(sqrtf(sq0), EPSV);   // 1/||Hs[c16]||
    float inv1 = 1.0f / fmaxf(sqrtf(sq1), EPSV);   // 1/||Hs[16+c16]||

    // ---- cosine MFMAs: cos[f][c] (8 MFMA) ----
    f32x4 cos0 = zro, cos1 = zro;
    #pragma unroll
    for (int kt = 0; kt < 4; ++kt) {
        cos0 = __builtin_amdgcn_mfma_f32_16x16x32_bf16(aF[0][kt], bcf[kt], cos0, 0, 0, 0);
        cos1 = __builtin_amdgcn_mfma_f32_16x16x32_bf16(aF[1][kt], bcf[kt], cos1, 0, 0, 0);
    }

    // ---- Linear: F_tj = relu(Hs @ W^T + b), 64 MFMA, tile-by-tile -> LDS ----
    #pragma unroll
    for (int nt = 0; nt < 8; ++nt) {
        bf16x8 bw0 = *(const bf16x8*)&Wb[((nt * 4) + 0) * 512 + lane * 8];
        bf16x8 bw1 = *(const bf16x8*)&Wb[((nt * 4) + 1) * 512 + lane * 8];
        bf16x8 bw2 = *(const bf16x8*)&Wb[((nt * 4) + 2) * 512 + lane * 8];
        bf16x8 bw3 = *(const bf16x8*)&Wb[((nt * 4) + 3) * 512 + lane * 8];
        f32x4 acc0 = zro, acc1 = zro;
        acc0 = __builtin_amdgcn_mfma_f32_16x16x32_bf16(aF[0][0], bw0, acc0, 0, 0, 0);
        acc1 = __builtin_amdgcn_mfma_f32_16x16x32_bf16(aF[1][0], bw0, acc1, 0, 0, 0);
        acc0 = __builtin_amdgcn_mfma_f32_16x16x32_bf16(aF[0][1], bw1, acc0, 0, 0, 0);
        acc1 = __builtin_amdgcn_mfma_f32_16x16x32_bf16(aF[1][1], bw1, acc1, 0, 0, 0);
        acc0 = __builtin_amdgcn_mfma_f32_16x16x32_bf16(aF[0][2], bw2, acc0, 0, 0, 0);
        acc1 = __builtin_amdgcn_mfma_f32_16x16x32_bf16(aF[1][2], bw2, acc1, 0, 0, 0);
        acc0 = __builtin_amdgcn_mfma_f32_16x16x32_bf16(aF[0][3], bw3, acc0, 0, 0, 0);
        acc1 = __builtin_amdgcn_mfma_f32_16x16x32_bf16(aF[1][3], bw3, acc1, 0, 0, 0);
        // lane holds F_tj[f = 16mt+4g+r][n = 16nt+c16]
        float bb = bvec[nt * 16 + c16];
        bf16x4 p0, p1;
        #pragma unroll
        for (int r = 0; r < 4; ++r) {
            p0[r] = f2bf(fmaxf(acc0[r] + bb, 0.f));
            p1[r] = f2bf(fmaxf(acc1[r] + bb, 0.f));
        }
        *(bf16x4*)&F_tjT[nt * 16 + c16][4 * g]      = p0;   // f = 4g+r
        *(bf16x4*)&F_tjT[nt * 16 + c16][16 + 4 * g] = p1;   // f = 16+4g+r
    }

    // ---- softmaxes fully in-register (C-layout: lane holds cos[f][c16],
    //      f = {4g+r, 16+4g+r}) ----
    float s0[4], s1[4];
    #pragma unroll
    for (int r = 0; r < 4; ++r) {
        s0[r] = 5.0f * cos0[r] * __shfl(inv0, 4 * g + r);        // f = 4g+r
        s1[r] = 5.0f * cos1[r] * __shfl(inv1, 4 * g + r);        // f = 16+4g+r
    }
    // w: softmax over features f (8 in-lane + xor16/xor32 over g)
    {
        float m = s0[0];
        #pragma unroll
        for (int r = 0; r < 4; ++r) { m = fmaxf(m, s0[r]); m = fmaxf(m, s1[r]); }
        m = fmaxf(m, __shfl_xor(m, 16));
        m = fmaxf(m, __shfl_xor(m, 32));
        float e0[4], e1[4], sum = 0.f;
        #pragma unroll
        for (int r = 0; r < 4; ++r) {
            e0[r] = __expf(s0[r] - m); e1[r] = __expf(s1[r] - m);
            sum += e0[r] + e1[r];
        }
        sum += __shfl_xor(sum, 16);
        sum += __shfl_xor(sum, 32);
        float inv = 1.0f / sum;
        #pragma unroll
        for (int r = 0; r < 4; ++r) {
            sWgT[c16][4 * g + r]      = f2bf(e0[r] * inv);   // w[f][c16], f=4g+r
            sWgT[c16][16 + 4 * g + r] = f2bf(e1[r] * inv);   // f=16+4g+r
        }
    }
    // w3: softmax over centers c (xor 1,2,4,8 within 16 lanes), fused with
    // importance contraction, then softmax over c of the result.
    {
        float t = 0.f;
        #pragma unroll
        for (int h = 0; h < 2; ++h) {
            #pragma unroll
            for (int r = 0; r < 4; ++r) {
                float sv = h ? s1[r] : s0[r];
                float m3 = sv;
                m3 = fmaxf(m3, __shfl_xor(m3, 1));
                m3 = fmaxf(m3, __shfl_xor(m3, 2));
                m3 = fmaxf(m3, __shfl_xor(m3, 4));
                m3 = fmaxf(m3, __shfl_xor(m3, 8));
                float e3 = __expf(sv - m3);
                float q3 = e3;
                q3 += __shfl_xor(q3, 1);
                q3 += __shfl_xor(q3, 2);
                q3 += __shfl_xor(q3, 4);
                q3 += __shfl_xor(q3, 8);
                t += (e3 / q3) * impv[h][r];
            }
        }
        t += __shfl_xor(t, 16);
        t += __shfl_xor(t, 32);
        float mi = t;
        mi = fmaxf(mi, __shfl_xor(mi, 1));
        mi = fmaxf(mi, __shfl_xor(mi, 2));
        mi = fmaxf(mi, __shfl_xor(mi, 4));
        mi = fmaxf(mi, __shfl_xor(mi, 8));
        float ei = __expf(t - mi);
        float si = ei;
        si += __shfl_xor(si, 1);
        si += __shfl_xor(si, 2);
        si += __shfl_xor(si, 4);
        si += __shfl_xor(si, 8);
        if (g == 0) imp_out[(size_t)site * Cc + c16] = ei / si;
    }

    // ---- aggregation: out[c][n] = sum_f w[f][c] * F_tj[f][n], 8 MFMA ----
    {
        bf16x8 wA = *(const bf16x8*)&sWgT[c16][8 * g];   // A[c=c16][f=8g+j]
        float* op = f_out + (size_t)site * (Cc * Dn);
        #pragma unroll
        for (int nt = 0; nt < 8; ++nt) {
            bf16x8 bF = *(const bf16x8*)&F_tjT[nt * 16 + c16][8 * g]; // B[f][n]
            f32x4 o = __builtin_amdgcn_mfma_f32_16x16x32_bf16(wA, bF, zro, 0, 0, 0);
            #pragma unroll
            for (int r = 0; r < 4; ++r)
                op[(4 * g + r) * Dn + nt * 16 + c16] = o[r];
        }
    }
}

// ---------------------------------------------------------------------------
extern "C" void kernel_launch(void* const* d_in, const int* in_sizes, int n_in,
                              void* d_out, int out_size, void* d_ws, size_t ws_size,
                              hipStream_t stream) {
    const float* Hs  = (const float*)d_in[0];
    const float* Cj  = (const float*)d_in[1];
    const float* W   = (const float*)d_in[2];
    const float* b   = (const float*)d_in[3];
    const float* imp = (const float*)d_in[4];

    float* f_out   = (float*)d_out;                          // [B,S,C,D]
    float* imp_out = f_out + (size_t)NSITE * Cc * Dn;        // [B,S,C]

    short* CnPack = (short*)d_ws;                            // 4 KB bf16 frags
    short* Wb     = CnPack + Cc * Dn;                        // 32 KB bf16 frags

    hipLaunchKernelGGL(normC_kernel, dim3(Cc), dim3(Dn), 0, stream, Cj, CnPack);
    hipLaunchKernelGGL(packW_kernel, dim3((Dn * Dn) / 256), dim3(256), 0, stream, W, Wb);
    hipLaunchKernelGGL(site_kernel, dim3(NSITE), dim3(64), 0, stream,
                       Hs, CnPack, Wb, b, imp, f_out, imp_out);
}